// Round 10
// baseline (37.889 us; speedup 1.0000x reference)
//
#include <hip/hip_runtime.h>

// EnergyPool2d: N=16, C=64, H=W=128, 3x3 windows stride 1 -> Ho=Wo=126.
// +1 at first-argmax flat index, -1 at first-argmin flat index per window.
// R10: anti-convoy schedule. One block = one plane, two half-plane LDS
// count buffers. Phase A: compute half-0. Phase B: issue half-0 writeout
// stores (fire-and-forget) THEN compute half-1 -> write drains under
// compute. Phase C: write half-1. Seam: halves overlap on window rows
// 62-63; LDS ownership guard (0 <= flat-bias < 8192) resolves it (R8).

#define HH 128
#define WW 128
#define PLANE (HH * WW)     // 16384
#define HPLANE (64 * WW)    // 8192
#define NPLANES (16 * 64)   // 1024
#define BLOCK 512

// First-occurrence argmax/argmin over a 3x3 window, row-major order
// (strict > / <). base = plane-flat index of window top-left.
__device__ __forceinline__ void scan9(float w0, float w1, float w2,
                                      float w3, float w4, float w5,
                                      float w6, float w7, float w8,
                                      int base, int bias, int* __restrict__ cnt) {
    float vmax = w0, vmin = w0;
    int omax = 0, omin = 0;
#define STEP(v, off)                                      \
    do {                                                  \
        if ((v) > vmax) { vmax = (v); omax = (off); }     \
        if ((v) < vmin) { vmin = (v); omin = (off); }     \
    } while (0)
    STEP(w1, 1);
    STEP(w2, 2);
    STEP(w3, WW);
    STEP(w4, WW + 1);
    STEP(w5, WW + 2);
    STEP(w6, 2 * WW);
    STEP(w7, 2 * WW + 1);
    STEP(w8, 2 * WW + 2);
#undef STEP
    const int iM = base + omax - bias;
    if ((unsigned)iM < HPLANE) atomicAdd(&cnt[iM], 1);
    const int im = base + omin - bias;
    if ((unsigned)im < HPLANE) atomicAdd(&cnt[im], -1);
}

// Compute all windows with top row in [row0, row0+64): 32 rt x 32 ct tiles
// of 2x4 windows, 2 tiles per thread. Owned rows: [bias/128, bias/128+64).
__device__ __forceinline__ void compute_half(const float* __restrict__ xp,
                                             int row0, int bias, int tid,
                                             int* __restrict__ cnt) {
#pragma unroll
    for (int it = 0; it < 2; ++it) {
        const int t = tid + it * BLOCK;
        const int rt = t >> 5;         // 0..31
        const int ct = t & 31;         // 0..31
        const int wr0 = row0 + rt * 2; // window rows wr0, wr0+1
        const int j0 = ct * 4;
        const float* __restrict__ p = xp + wr0 * WW + j0;

        const float4 a0 = *(const float4*)(p);
        const float4 a1 = *(const float4*)(p + WW);
        const float4 a2 = *(const float4*)(p + 2 * WW);
        const float4 a3 = *(const float4*)(p + 3 * WW);
        float4 b0, b1, b2, b3;
        if (ct < 31) {
            b0 = *(const float4*)(p + 4);
            b1 = *(const float4*)(p + WW + 4);
            b2 = *(const float4*)(p + 2 * WW + 4);
            b3 = *(const float4*)(p + 3 * WW + 4);
        } else {
            b0 = b1 = b2 = b3 = make_float4(0.f, 0.f, 0.f, 0.f);
        }
        const float r0[8] = {a0.x, a0.y, a0.z, a0.w, b0.x, b0.y, b0.z, b0.w};
        const float r1[8] = {a1.x, a1.y, a1.z, a1.w, b1.x, b1.y, b1.z, b1.w};
        const float r2[8] = {a2.x, a2.y, a2.z, a2.w, b2.x, b2.y, b2.z, b2.w};
        const float r3[8] = {a3.x, a3.y, a3.z, a3.w, b3.x, b3.y, b3.z, b3.w};

        const int nw = (ct < 31) ? 4 : 2;
        const int base0 = wr0 * WW + j0;
#pragma unroll
        for (int c = 0; c < 4; ++c) {
            if (c < nw) {
                scan9(r0[c], r0[c + 1], r0[c + 2],
                      r1[c], r1[c + 1], r1[c + 2],
                      r2[c], r2[c + 1], r2[c + 2], base0 + c, bias, cnt);
                scan9(r1[c], r1[c + 1], r1[c + 2],
                      r2[c], r2[c + 1], r2[c + 2],
                      r3[c], r3[c + 1], r3[c + 2], base0 + WW + c, bias, cnt);
            }
        }
    }
}

__global__ __launch_bounds__(BLOCK, 4)
void energy_pool2d_kernel(const float* __restrict__ x, float* __restrict__ out) {
    __shared__ int cnt[2][HPLANE]; // 64 KB

    const int tid = threadIdx.x;
    const int plane = blockIdx.x;
    const float* __restrict__ xp = x + (size_t)plane * PLANE;
    float* __restrict__ op = out + (size_t)plane * PLANE;

    // Zero both half-plane count buffers.
    int4* cz = (int4*)&cnt[0][0];
#pragma unroll
    for (int i = 0; i < 2 * HPLANE / 4 / BLOCK; ++i)
        cz[tid + i * BLOCK] = make_int4(0, 0, 0, 0);
    __syncthreads();

    // Phase A: windows rows 0..63 -> cnt[0] (owns plane rows 0..63).
    compute_half(xp, 0, 0, tid, &cnt[0][0]);
    __syncthreads();

    // Phase B: issue writeout of half-0 (stores drain during compute),
    // then windows rows 62..125 -> cnt[1] (owns plane rows 64..127).
    {
        const int4* c4 = (const int4*)&cnt[0][0];
        float4* __restrict__ o4 = (float4*)op;
#pragma unroll
        for (int i = 0; i < HPLANE / 4 / BLOCK; ++i) {
            const int4 ci = c4[tid + i * BLOCK];
            o4[tid + i * BLOCK] =
                make_float4((float)ci.x, (float)ci.y, (float)ci.z, (float)ci.w);
        }
    }
    compute_half(xp, 62, HPLANE, tid, &cnt[1][0]);
    __syncthreads();

    // Phase C: writeout half-1 (plane rows 64..127).
    {
        const int4* c4 = (const int4*)&cnt[1][0];
        float4* __restrict__ o4 = (float4*)(op + HPLANE);
#pragma unroll
        for (int i = 0; i < HPLANE / 4 / BLOCK; ++i) {
            const int4 ci = c4[tid + i * BLOCK];
            o4[tid + i * BLOCK] =
                make_float4((float)ci.x, (float)ci.y, (float)ci.z, (float)ci.w);
        }
    }
}

extern "C" void kernel_launch(void* const* d_in, const int* in_sizes, int n_in,
                              void* d_out, int out_size, void* d_ws, size_t ws_size,
                              hipStream_t stream) {
    const float* x = (const float*)d_in[0];
    float* out = (float*)d_out;
    energy_pool2d_kernel<<<NPLANES, BLOCK, 0, stream>>>(x, out);
}

// Round 11
// 34.082 us; speedup vs baseline: 1.1117x; 1.1117x over previous
//
#include <hip/hip_runtime.h>

// EnergyPool2d: N=16, C=64, H=W=128, 3x3 windows stride 1 -> Ho=Wo=126.
// +1 at first-argmax flat index, -1 at first-argmin flat index per window.
// R11 = R8 (512 thr, half-plane 32KB LDS count, ownership guard, exactly
// 2 tiles/thread) + BOTH tiles' 16 float4 loads hoisted before any
// scan/atomic. Rationale: atomicAdd is a memory-reorder fence, so the
// compiler cannot hoist tile-2 loads above tile-1 atomics; done in source,
// each wave eats one load-use stall instead of two serialized ones.

#define HH 128
#define WW 128
#define PLANE (HH * WW)     // 16384
#define HROWS 64
#define HPLANE (HROWS * WW) // 8192
#define NPLANES (16 * 64)   // 1024
#define BLOCK 512

// First-occurrence argmax/argmin over a 3x3 window, row-major scan order
// (strict > / <). Adds guarded by half-plane ownership (seam resolution).
__device__ __forceinline__ void scan9(float w0, float w1, float w2,
                                      float w3, float w4, float w5,
                                      float w6, float w7, float w8,
                                      int base, int bias, int* __restrict__ cnt) {
    float vmax = w0, vmin = w0;
    int omax = 0, omin = 0;
#define STEP(v, off)                                      \
    do {                                                  \
        if ((v) > vmax) { vmax = (v); omax = (off); }     \
        if ((v) < vmin) { vmin = (v); omin = (off); }     \
    } while (0)
    STEP(w1, 1);
    STEP(w2, 2);
    STEP(w3, WW);
    STEP(w4, WW + 1);
    STEP(w5, WW + 2);
    STEP(w6, 2 * WW);
    STEP(w7, 2 * WW + 1);
    STEP(w8, 2 * WW + 2);
#undef STEP
    const int iM = base + omax - bias;
    if ((unsigned)iM < HPLANE) atomicAdd(&cnt[iM], 1);
    const int im = base + omin - bias;
    if ((unsigned)im < HPLANE) atomicAdd(&cnt[im], -1);
}

__global__ __launch_bounds__(BLOCK, 4)
void energy_pool2d_kernel(const float* __restrict__ x, float* __restrict__ out) {
    __shared__ int cnt[HPLANE]; // 32 KB

    const int tid = threadIdx.x;
    const int plane = blockIdx.x >> 1;
    const int half = blockIdx.x & 1;
    const float* __restrict__ xp = x + (size_t)plane * PLANE;

    // Zero the LDS half-plane.
    int4* c4 = (int4*)cnt;
#pragma unroll
    for (int i = 0; i < HPLANE / 4 / BLOCK; ++i)
        c4[tid + i * BLOCK] = make_int4(0, 0, 0, 0);
    __syncthreads();

    const int row0 = half ? 62 : 0;   // first window row of this half
    const int bias = half * HPLANE;

    // Two 4-wide x 2-tall tiles per thread. Note (tid+512)&31 == tid&31,
    // so both tiles share ct (same edge handling) and differ by rt+16.
    const int rt = tid >> 5;          // 0..15
    const int ct = tid & 31;          // 0..31
    const int j0 = ct * 4;
    const bool cfull = (ct < 31);
    const int wrA = row0 + rt * 2;          // tile A window rows
    const int wrB = row0 + (rt + 16) * 2;   // tile B window rows
    const float* __restrict__ pA = xp + wrA * WW + j0;
    const float* __restrict__ pB = xp + wrB * WW + j0;

    // ---- Hoisted loads: ALL 16 float4 loads issued before any compute ----
    const float4 a0 = *(const float4*)(pA);
    const float4 a1 = *(const float4*)(pA + WW);
    const float4 a2 = *(const float4*)(pA + 2 * WW);
    const float4 a3 = *(const float4*)(pA + 3 * WW);
    const float4 c0 = *(const float4*)(pB);
    const float4 c1 = *(const float4*)(pB + WW);
    const float4 c2 = *(const float4*)(pB + 2 * WW);
    const float4 c3 = *(const float4*)(pB + 3 * WW);
    float4 b0, b1, b2, b3, d0, d1, d2, d3;
    if (cfull) {
        b0 = *(const float4*)(pA + 4);
        b1 = *(const float4*)(pA + WW + 4);
        b2 = *(const float4*)(pA + 2 * WW + 4);
        b3 = *(const float4*)(pA + 3 * WW + 4);
        d0 = *(const float4*)(pB + 4);
        d1 = *(const float4*)(pB + WW + 4);
        d2 = *(const float4*)(pB + 2 * WW + 4);
        d3 = *(const float4*)(pB + 3 * WW + 4);
    } else {
        b0 = b1 = b2 = b3 = make_float4(0.f, 0.f, 0.f, 0.f);
        d0 = d1 = d2 = d3 = make_float4(0.f, 0.f, 0.f, 0.f);
    }

    const float rA0[8] = {a0.x, a0.y, a0.z, a0.w, b0.x, b0.y, b0.z, b0.w};
    const float rA1[8] = {a1.x, a1.y, a1.z, a1.w, b1.x, b1.y, b1.z, b1.w};
    const float rA2[8] = {a2.x, a2.y, a2.z, a2.w, b2.x, b2.y, b2.z, b2.w};
    const float rA3[8] = {a3.x, a3.y, a3.z, a3.w, b3.x, b3.y, b3.z, b3.w};
    const float rB0[8] = {c0.x, c0.y, c0.z, c0.w, d0.x, d0.y, d0.z, d0.w};
    const float rB1[8] = {c1.x, c1.y, c1.z, c1.w, d1.x, d1.y, d1.z, d1.w};
    const float rB2[8] = {c2.x, c2.y, c2.z, c2.w, d2.x, d2.y, d2.z, d2.w};
    const float rB3[8] = {c3.x, c3.y, c3.z, c3.w, d3.x, d3.y, d3.z, d3.w};

    const int nw = cfull ? 4 : 2;
    const int baseA = wrA * WW + j0;
    const int baseB = wrB * WW + j0;
#pragma unroll
    for (int c = 0; c < 4; ++c) {
        if (c < nw) {
            scan9(rA0[c], rA0[c + 1], rA0[c + 2],
                  rA1[c], rA1[c + 1], rA1[c + 2],
                  rA2[c], rA2[c + 1], rA2[c + 2], baseA + c, bias, cnt);
            scan9(rA1[c], rA1[c + 1], rA1[c + 2],
                  rA2[c], rA2[c + 1], rA2[c + 2],
                  rA3[c], rA3[c + 1], rA3[c + 2], baseA + WW + c, bias, cnt);
            scan9(rB0[c], rB0[c + 1], rB0[c + 2],
                  rB1[c], rB1[c + 1], rB1[c + 2],
                  rB2[c], rB2[c + 1], rB2[c + 2], baseB + c, bias, cnt);
            scan9(rB1[c], rB1[c + 1], rB1[c + 2],
                  rB2[c], rB2[c + 1], rB2[c + 2],
                  rB3[c], rB3[c + 1], rB3[c + 2], baseB + WW + c, bias, cnt);
        }
    }
    __syncthreads();

    // Coalesced writeout of this half (fully overwritten -> no pre-zero).
    float4* __restrict__ o4 = (float4*)(out + (size_t)plane * PLANE + bias);
#pragma unroll
    for (int i = 0; i < HPLANE / 4 / BLOCK; ++i) {
        const int4 ci = c4[tid + i * BLOCK];
        o4[tid + i * BLOCK] =
            make_float4((float)ci.x, (float)ci.y, (float)ci.z, (float)ci.w);
    }
}

extern "C" void kernel_launch(void* const* d_in, const int* in_sizes, int n_in,
                              void* d_out, int out_size, void* d_ws, size_t ws_size,
                              hipStream_t stream) {
    const float* x = (const float*)d_in[0];
    float* out = (float*)d_out;
    energy_pool2d_kernel<<<NPLANES * 2, BLOCK, 0, stream>>>(x, out);
}